// Round 14
// baseline (212.287 us; speedup 1.0000x reference)
//
#include <hip/hip_runtime.h>
#include <hip/hip_bf16.h>

// MultiDilatelocalAttention, round 14:
// - QKV GEMM: A direct-to-VGPR per wave (reg-prefetch depth 1, no barrier
//   coupling — A has ZERO intra-block reuse in a 2x2 wave grid, so LDS-staging
//   it only added lockstep), B via 4-buffer LDS ring (single barrier/iter,
//   uniform vmcnt(6) gate). LDS 32KB.
// - proj GEMM round-8 exact; attn round-13 (XCD-chunked); conv_all unchanged.

#define NTOK 50176
#define ROWQKV 1152
#define CDIM 384

typedef _Float16 half2v __attribute__((ext_vector_type(2)));
typedef _Float16 half8 __attribute__((ext_vector_type(8)));
typedef float floatx4 __attribute__((ext_vector_type(4)));

typedef __attribute__((address_space(1))) const unsigned int GU32;
typedef __attribute__((address_space(3))) unsigned int LU32;

// ---------------- fused fp32 -> fp16 conversion: x, w_qkv, w_proj ----------------
#define N_X4 (NTOK * CDIM / 4)
#define N_Q4 (ROWQKV * CDIM / 4)
#define N_P4 (CDIM * CDIM / 4)

__global__ __launch_bounds__(256) void conv_all(const float* __restrict__ x,
                                                const float* __restrict__ wq,
                                                const float* __restrict__ wp,
                                                _Float16* __restrict__ xh,
                                                _Float16* __restrict__ wqh,
                                                _Float16* __restrict__ wph) {
  const int total = N_X4 + N_Q4 + N_P4;
  int i = blockIdx.x * 256 + threadIdx.x;
  const int stride = gridDim.x * 256;
  for (; i < total; i += stride) {
    const float* src;
    _Float16* dst;
    int k;
    if (i < N_X4) { src = x; dst = xh; k = i; }
    else if (i < N_X4 + N_Q4) { src = wq; dst = wqh; k = i - N_X4; }
    else { src = wp; dst = wph; k = i - N_X4 - N_Q4; }
    float4 v = ((const float4*)src)[k];
    union { _Float16 h[4]; uint2 u; } o;
    o.h[0] = (_Float16)v.x; o.h[1] = (_Float16)v.y;
    o.h[2] = (_Float16)v.z; o.h[3] = (_Float16)v.w;
    ((uint2*)dst)[k] = o.u;
  }
}

// ---------------- QKV GEMM: A-direct + B-LDS-ring ----------------
// C[50176][1152] = A[50176][384] * B[1152][384]^T, f16 out. 128x128 tile,
// 4 waves 2x2, 12 K-iters of BK=32. Per iter: loadA(t+1)->regs (4x16B, per
// wave, no sync), stageB(t+2)->ring buf (2 gload_lds), vmcnt(6) [drains
// exactly A(t)+B(t+1); B(t) older, A(t+1)/B(t+2) stay in flight], ONE
// barrier, ds_read B frags, 16 MFMA (setprio). XCD-chunked remap.
__global__ __launch_bounds__(256) void gemm_qkv_ad(const _Float16* __restrict__ A,
                                                   const _Float16* __restrict__ B,
                                                   _Float16* __restrict__ C) {
  __shared__ _Float16 Bs4[4][128 * 32];
  const int tid = threadIdx.x;
  const int lane = tid & 63;
  const int wv = tid >> 6;
  const int wr = wv >> 1, wc = wv & 1;
  const int K = CDIM, N = ROWQKV;

  const int p = blockIdx.x;
  const int l = (p & 7) * (gridDim.x >> 3) + (p >> 3);
  const int nN = N >> 7;  // 9
  const size_t row0 = (size_t)(l / nN) * 128;
  const int col0 = (l % nN) * 128;

  // B staging (ring of 4): source-swizzled granules, linear LDS dest
  const int srow = tid >> 2;
  const int gslot = (tid & 3) ^ ((srow >> 1) & 3);
  const _Float16* Bbase = B + ((size_t)(col0 + srow)) * (size_t)K + gslot * 8;
  char* BsB = (char*)Bs4;
  auto stageB = [&](int t) {
    const int buf = t & 3;
    const int k0 = t * 32;
    __builtin_amdgcn_global_load_lds((GU32*)(Bbase + k0),
                                     (LU32*)(BsB + buf * 8192 + tid * 16), 16, 0, 0);
    __builtin_amdgcn_global_load_lds((GU32*)(Bbase + (size_t)64 * K + k0),
                                     (LU32*)(BsB + buf * 8192 + tid * 16 + 4096), 16, 0, 0);
  };

  // A direct: lane (fr, fq) reads A[row0 + wr*64 + f*16 + fr][t*32 + fq*8 ..+8]
  const int fr = lane & 15;
  const int fq = lane >> 4;
  const int rpos = (fq ^ ((fr >> 1) & 3)) * 8;  // B ds_read swizzle (matches round-8)
  const _Float16* Abase = A + (row0 + wr * 64 + fr) * (size_t)K + fq * 8;

  half8 aC[4], aN[4];
  auto loadA = [&](int t, half8* dst) {
    const int k0 = t * 32;
#pragma unroll
    for (int f = 0; f < 4; ++f)
      dst[f] = *(const half8*)(Abase + (size_t)f * 16 * K + k0);
  };

  floatx4 acc[4][4];
#pragma unroll
  for (int i = 0; i < 4; ++i)
#pragma unroll
    for (int j = 0; j < 4; ++j) acc[i][j] = (floatx4){0.f, 0.f, 0.f, 0.f};

  // prologue: A(0) to regs; B(0), B(1) staged
  loadA(0, aC);
  stageB(0);
  stageB(1);

  auto body = [&](int t, half8* aUse, half8* aPre) {
    if (t + 1 < 12) loadA(t + 1, aPre);   // 4 VMEM (per-wave, barrier-free)
    if (t + 2 < 12) stageB(t + 2);        // 2 VMEM (ring, WAR-safe at dist 2)
    if (t == 11) asm volatile("s_waitcnt vmcnt(0)" ::: "memory");
    else         asm volatile("s_waitcnt vmcnt(6)" ::: "memory");
    __builtin_amdgcn_s_barrier();          // B(t) visible block-wide
    __builtin_amdgcn_sched_barrier(0);
    half8 bf[4];
#pragma unroll
    for (int f = 0; f < 4; ++f)
      bf[f] = *(const half8*)&Bs4[t & 3][(wc * 64 + f * 16 + fr) * 32 + rpos];
    __builtin_amdgcn_s_setprio(1);
#pragma unroll
    for (int i = 0; i < 4; ++i)
#pragma unroll
      for (int j = 0; j < 4; ++j)
        acc[i][j] = __builtin_amdgcn_mfma_f32_16x16x32_f16(aUse[i], bf[j], acc[i][j], 0, 0, 0);
    __builtin_amdgcn_s_setprio(0);
  };

#pragma unroll
  for (int tt = 0; tt < 6; ++tt) {   // unroll-by-2: static reg sets (rule #20)
    body(2 * tt, aC, aN);
    body(2 * tt + 1, aN, aC);
  }

  // epilogue: C/D layout col=lane&15, row=(lane>>4)*4+reg
  const int crow = wr * 64 + (lane >> 4) * 4;
  const int ccol = wc * 64 + (lane & 15);
#pragma unroll
  for (int fm = 0; fm < 4; ++fm) {
#pragma unroll
    for (int fn = 0; fn < 4; ++fn) {
      const size_t r0 = (row0 + crow + fm * 16) * (size_t)N + col0 + ccol + fn * 16;
#pragma unroll
      for (int j = 0; j < 4; ++j) C[r0 + (size_t)j * N] = (_Float16)acc[fm][fn][j];
    }
  }
}

// ---------------- proj GEMM (round-8 exact): C = A * B^T, dbuf + vmcnt(4) ----------------
template <bool HALF_OUT>
__global__ __launch_bounds__(256) void gemm3(const _Float16* __restrict__ A,
                                             const _Float16* __restrict__ B,
                                             const float* __restrict__ bias,
                                             void* __restrict__ Cout,
                                             int N, int K) {
  __shared__ _Float16 Asl[2][128 * 32];
  __shared__ _Float16 Bsl[2][128 * 32];
  const int tid = threadIdx.x;
  const int lane = tid & 63;
  const int wv = tid >> 6;
  const int wr = wv >> 1, wc = wv & 1;

  const int nN = N >> 7;
  const int p = blockIdx.x;
  const int l = (p & 7) * (gridDim.x >> 3) + (p >> 3);
  const size_t row0 = (size_t)(l / nN) * 128;
  const int col0 = (l % nN) * 128;
  const int NT = K / 32;

  const int srow = tid >> 2;
  const int gslot = (tid & 3) ^ ((srow >> 1) & 3);
  const _Float16* Abase = A + (row0 + srow) * (size_t)K + gslot * 8;
  const _Float16* Bbase = B + ((size_t)(col0 + srow)) * (size_t)K + gslot * 8;
  char* AsB = (char*)Asl;
  char* BsB = (char*)Bsl;

  auto stage = [&](int k0, int buf) {
    __builtin_amdgcn_global_load_lds((GU32*)(Abase + k0),
                                     (LU32*)(AsB + buf * 8192 + tid * 16), 16, 0, 0);
    __builtin_amdgcn_global_load_lds((GU32*)(Abase + (size_t)64 * K + k0),
                                     (LU32*)(AsB + buf * 8192 + tid * 16 + 4096), 16, 0, 0);
    __builtin_amdgcn_global_load_lds((GU32*)(Bbase + k0),
                                     (LU32*)(BsB + buf * 8192 + tid * 16), 16, 0, 0);
    __builtin_amdgcn_global_load_lds((GU32*)(Bbase + (size_t)64 * K + k0),
                                     (LU32*)(BsB + buf * 8192 + tid * 16 + 4096), 16, 0, 0);
  };

  const int fr = lane & 15;
  const int fq = lane >> 4;
  const int rpos = (fq ^ ((fr >> 1) & 3)) * 8;

  floatx4 acc[4][4];
#pragma unroll
  for (int i = 0; i < 4; ++i)
#pragma unroll
    for (int j = 0; j < 4; ++j) acc[i][j] = (floatx4){0.f, 0.f, 0.f, 0.f};

  stage(0, 0);
  asm volatile("s_waitcnt vmcnt(0)" ::: "memory");
  __builtin_amdgcn_s_barrier();

  int cur = 0;
  for (int t = 0; t < NT; ++t) {
    if (t + 1 < NT) {
      stage((t + 1) * 32, cur ^ 1);
      asm volatile("s_waitcnt vmcnt(4)" ::: "memory");
    } else {
      asm volatile("s_waitcnt vmcnt(0)" ::: "memory");
    }
    __builtin_amdgcn_s_barrier();
    __builtin_amdgcn_sched_barrier(0);
    half8 af[4], bf[4];
#pragma unroll
    for (int f = 0; f < 4; ++f) {
      af[f] = *(const half8*)&Asl[cur][(wr * 64 + f * 16 + fr) * 32 + rpos];
      bf[f] = *(const half8*)&Bsl[cur][(wc * 64 + f * 16 + fr) * 32 + rpos];
    }
#pragma unroll
    for (int i = 0; i < 4; ++i)
#pragma unroll
      for (int j = 0; j < 4; ++j)
        acc[i][j] = __builtin_amdgcn_mfma_f32_16x16x32_f16(af[i], bf[j], acc[i][j], 0, 0, 0);
    __builtin_amdgcn_sched_barrier(0);
    __builtin_amdgcn_s_barrier();
    cur ^= 1;
  }

  const int crow = wr * 64 + (lane >> 4) * 4;
  const int ccol = wc * 64 + (lane & 15);
#pragma unroll
  for (int fm = 0; fm < 4; ++fm) {
#pragma unroll
    for (int fn = 0; fn < 4; ++fn) {
      const size_t r0 = (row0 + crow + fm * 16) * (size_t)N + col0 + ccol + fn * 16;
      if (HALF_OUT) {
        _Float16* Cc = (_Float16*)Cout;
#pragma unroll
        for (int j = 0; j < 4; ++j) Cc[r0 + (size_t)j * N] = (_Float16)acc[fm][fn][j];
      } else {
        float* Cc = (float*)Cout;
        const float bz = bias[col0 + ccol + fn * 16];
#pragma unroll
        for (int j = 0; j < 4; ++j) Cc[r0 + (size_t)j * N] = acc[fm][fn][j] + bz;
      }
    }
  }
}

// ---------------- Local attention: one thread per (token, head), XCD-chunked ----------------
__global__ __launch_bounds__(256) void attn_kernel(const _Float16* __restrict__ qkv,
                                                   _Float16* __restrict__ y) {
  const int p = blockIdx.x;
  const int l = (p & 7) * (gridDim.x >> 3) + (p >> 3);
  const int idx = l * 256 + threadIdx.x;  // token*12 + head
  const int head = idx % 12;
  const int token = idx / 12;
  const int branch = head >> 2;
  const int dil = branch + 1;
  const int cbase = branch * 128 + (head & 3) * 32;
  const int xx = token % 56;
  const int yy = (token / 56) % 56;
  const int bimg = token / 3136;
  const float scale = 0.17677669529663687f;  // 1/sqrt(32)

  const _Float16* qp = qkv + (size_t)token * ROWQKV + cbase;
  half2v qh[16];
  *(half8*)&qh[0] = *(const half8*)(qp);
  *(half8*)&qh[4] = *(const half8*)(qp + 8);
  *(half8*)&qh[8] = *(const half8*)(qp + 16);
  *(half8*)&qh[12] = *(const half8*)(qp + 24);

  const size_t nbase = (size_t)bimg * 3136;

  float lg[9];
#pragma unroll
  for (int j = 0; j < 9; ++j) {
    const int ny = yy + (j / 3 - 1) * dil;
    const int nx = xx + (j % 3 - 1) * dil;
    float d = 0.f;
    if ((unsigned)ny < 56u && (unsigned)nx < 56u) {
      const _Float16* kp = qkv + (nbase + ny * 56 + nx) * ROWQKV + 384 + cbase;
      half2v kh[16];
      *(half8*)&kh[0] = *(const half8*)(kp);
      *(half8*)&kh[4] = *(const half8*)(kp + 8);
      *(half8*)&kh[8] = *(const half8*)(kp + 16);
      *(half8*)&kh[12] = *(const half8*)(kp + 24);
#if __has_builtin(__builtin_amdgcn_fdot2)
#pragma unroll
      for (int c = 0; c < 16; ++c) d = __builtin_amdgcn_fdot2(qh[c], kh[c], d, false);
#else
#pragma unroll
      for (int c = 0; c < 16; ++c)
        d += (float)qh[c][0] * (float)kh[c][0] + (float)qh[c][1] * (float)kh[c][1];
#endif
    }
    lg[j] = d * scale;
  }

  float m = lg[0];
#pragma unroll
  for (int j = 1; j < 9; ++j) m = fmaxf(m, lg[j]);
  float s = 0.f;
#pragma unroll
  for (int j = 0; j < 9; ++j) { lg[j] = expf(lg[j] - m); s += lg[j]; }
  const float rs = 1.f / s;

  float out[32];
#pragma unroll
  for (int c = 0; c < 32; ++c) out[c] = 0.f;
#pragma unroll
  for (int j = 0; j < 9; ++j) {
    const int ny = yy + (j / 3 - 1) * dil;
    const int nx = xx + (j % 3 - 1) * dil;
    if ((unsigned)ny < 56u && (unsigned)nx < 56u) {
      const _Float16* vp = qkv + (nbase + ny * 56 + nx) * ROWQKV + 768 + cbase;
      half8 vh[4];
      vh[0] = *(const half8*)(vp);
      vh[1] = *(const half8*)(vp + 8);
      vh[2] = *(const half8*)(vp + 16);
      vh[3] = *(const half8*)(vp + 24);
      const float pw = lg[j];
#pragma unroll
      for (int g = 0; g < 4; ++g)
#pragma unroll
        for (int e = 0; e < 8; ++e) out[g * 8 + e] = fmaf(pw, (float)vh[g][e], out[g * 8 + e]);
    }
  }

  _Float16* yp = y + (size_t)token * CDIM + cbase;
  half8 oh[4];
#pragma unroll
  for (int g = 0; g < 4; ++g) {
#pragma unroll
    for (int e = 0; e < 8; ++e) oh[g][e] = (_Float16)(out[g * 8 + e] * rs);
    *(half8*)(yp + g * 8) = oh[g];
  }
}

extern "C" void kernel_launch(void* const* d_in, const int* in_sizes, int n_in,
                              void* d_out, int out_size, void* d_ws, size_t ws_size,
                              hipStream_t stream) {
  const float* x = (const float*)d_in[0];       // [16,56,56,384]
  const float* w_qkv = (const float*)d_in[1];   // [1152,384]
  const float* w_proj = (const float*)d_in[2];  // [384,384]
  const float* b_proj = (const float*)d_in[3];  // [384]
  float* out = (float*)d_out;                   // [50176,384]

  _Float16* xh = (_Float16*)d_ws;                     // 50176*384
  _Float16* wqh = xh + (size_t)NTOK * CDIM;           // 1152*384
  _Float16* wph = wqh + (size_t)ROWQKV * CDIM;        // 384*384
  _Float16* qkvh = wph + (size_t)CDIM * CDIM;         // 50176*1152
  _Float16* yh = qkvh + (size_t)NTOK * ROWQKV;        // 50176*384

  conv_all<<<2048, 256, 0, stream>>>(x, w_qkv, w_proj, xh, wqh, wph);

  gemm_qkv_ad<<<(NTOK / 128) * (ROWQKV / 128), 256, 0, stream>>>(xh, wqh, qkvh);

  attn_kernel<<<(NTOK * 12) / 256, 256, 0, stream>>>(qkvh, yh);

  gemm3<false><<<(NTOK / 128) * (CDIM / 128), 256, 0, stream>>>(
      yh, wph, b_proj, out, CDIM, CDIM);
}

// Round 15
// 191.053 us; speedup vs baseline: 1.1111x; 1.1111x over previous
//
#include <hip/hip_runtime.h>
#include <hip/hip_bf16.h>

// MultiDilatelocalAttention, round 15: round 13 + LDS-tiled attention redo.
// attn: ONE launch, grid 2352 = 49 tiles x 16 imgs x 3 branches, XCD-chunked.
// Per block: stage k-halo (H^2 x 256B, stride 272) -> QK dots -> barrier ->
// stage v-halo into the SAME buffer -> softmax+PV. LDS 53KB -> 3 blocks/CU
// (fixes round-12's 1-block/CU occupancy failure). GEMMs/conv = round 13.

#define NTOK 50176
#define ROWQKV 1152
#define CDIM 384

typedef _Float16 half2v __attribute__((ext_vector_type(2)));
typedef _Float16 half8 __attribute__((ext_vector_type(8)));
typedef float floatx4 __attribute__((ext_vector_type(4)));

typedef __attribute__((address_space(1))) const unsigned int GU32;
typedef __attribute__((address_space(3))) unsigned int LU32;

// ---------------- fused fp32 -> fp16 conversion: x, w_qkv, w_proj ----------------
#define N_X4 (NTOK * CDIM / 4)
#define N_Q4 (ROWQKV * CDIM / 4)
#define N_P4 (CDIM * CDIM / 4)

__global__ __launch_bounds__(256) void conv_all(const float* __restrict__ x,
                                                const float* __restrict__ wq,
                                                const float* __restrict__ wp,
                                                _Float16* __restrict__ xh,
                                                _Float16* __restrict__ wqh,
                                                _Float16* __restrict__ wph) {
  const int total = N_X4 + N_Q4 + N_P4;
  int i = blockIdx.x * 256 + threadIdx.x;
  const int stride = gridDim.x * 256;
  for (; i < total; i += stride) {
    const float* src;
    _Float16* dst;
    int k;
    if (i < N_X4) { src = x; dst = xh; k = i; }
    else if (i < N_X4 + N_Q4) { src = wq; dst = wqh; k = i - N_X4; }
    else { src = wp; dst = wph; k = i - N_X4 - N_Q4; }
    float4 v = ((const float4*)src)[k];
    union { _Float16 h[4]; uint2 u; } o;
    o.h[0] = (_Float16)v.x; o.h[1] = (_Float16)v.y;
    o.h[2] = (_Float16)v.z; o.h[3] = (_Float16)v.w;
    ((uint2*)dst)[k] = o.u;
  }
}

// ---------------- f16 MFMA GEMM (round-8 exact): C = A * B^T, dbuf + vmcnt(4) ----------------
template <bool HALF_OUT>
__global__ __launch_bounds__(256) void gemm3(const _Float16* __restrict__ A,
                                             const _Float16* __restrict__ B,
                                             const float* __restrict__ bias,
                                             void* __restrict__ Cout,
                                             int N, int K) {
  __shared__ _Float16 Asl[2][128 * 32];
  __shared__ _Float16 Bsl[2][128 * 32];
  const int tid = threadIdx.x;
  const int lane = tid & 63;
  const int wv = tid >> 6;
  const int wr = wv >> 1, wc = wv & 1;

  const int nN = N >> 7;
  const int p = blockIdx.x;
  const int l = (p & 7) * (gridDim.x >> 3) + (p >> 3);
  const size_t row0 = (size_t)(l / nN) * 128;
  const int col0 = (l % nN) * 128;
  const int NT = K / 32;

  const int srow = tid >> 2;
  const int gslot = (tid & 3) ^ ((srow >> 1) & 3);
  const _Float16* Abase = A + (row0 + srow) * (size_t)K + gslot * 8;
  const _Float16* Bbase = B + ((size_t)(col0 + srow)) * (size_t)K + gslot * 8;
  char* AsB = (char*)Asl;
  char* BsB = (char*)Bsl;

  auto stage = [&](int k0, int buf) {
    __builtin_amdgcn_global_load_lds((GU32*)(Abase + k0),
                                     (LU32*)(AsB + buf * 8192 + tid * 16), 16, 0, 0);
    __builtin_amdgcn_global_load_lds((GU32*)(Abase + (size_t)64 * K + k0),
                                     (LU32*)(AsB + buf * 8192 + tid * 16 + 4096), 16, 0, 0);
    __builtin_amdgcn_global_load_lds((GU32*)(Bbase + k0),
                                     (LU32*)(BsB + buf * 8192 + tid * 16), 16, 0, 0);
    __builtin_amdgcn_global_load_lds((GU32*)(Bbase + (size_t)64 * K + k0),
                                     (LU32*)(BsB + buf * 8192 + tid * 16 + 4096), 16, 0, 0);
  };

  const int fr = lane & 15;
  const int fq = lane >> 4;
  const int rpos = (fq ^ ((fr >> 1) & 3)) * 8;

  floatx4 acc[4][4];
#pragma unroll
  for (int i = 0; i < 4; ++i)
#pragma unroll
    for (int j = 0; j < 4; ++j) acc[i][j] = (floatx4){0.f, 0.f, 0.f, 0.f};

  stage(0, 0);
  asm volatile("s_waitcnt vmcnt(0)" ::: "memory");
  __builtin_amdgcn_s_barrier();

  int cur = 0;
  for (int t = 0; t < NT; ++t) {
    if (t + 1 < NT) {
      stage((t + 1) * 32, cur ^ 1);
      asm volatile("s_waitcnt vmcnt(4)" ::: "memory");
    } else {
      asm volatile("s_waitcnt vmcnt(0)" ::: "memory");
    }
    __builtin_amdgcn_s_barrier();
    __builtin_amdgcn_sched_barrier(0);
    half8 af[4], bf[4];
#pragma unroll
    for (int f = 0; f < 4; ++f) {
      af[f] = *(const half8*)&Asl[cur][(wr * 64 + f * 16 + fr) * 32 + rpos];
      bf[f] = *(const half8*)&Bsl[cur][(wc * 64 + f * 16 + fr) * 32 + rpos];
    }
#pragma unroll
    for (int i = 0; i < 4; ++i)
#pragma unroll
      for (int j = 0; j < 4; ++j)
        acc[i][j] = __builtin_amdgcn_mfma_f32_16x16x32_f16(af[i], bf[j], acc[i][j], 0, 0, 0);
    __builtin_amdgcn_sched_barrier(0);
    __builtin_amdgcn_s_barrier();
    cur ^= 1;
  }

  const int crow = wr * 64 + (lane >> 4) * 4;
  const int ccol = wc * 64 + (lane & 15);
#pragma unroll
  for (int fm = 0; fm < 4; ++fm) {
#pragma unroll
    for (int fn = 0; fn < 4; ++fn) {
      const size_t r0 = (row0 + crow + fm * 16) * (size_t)N + col0 + ccol + fn * 16;
      if (HALF_OUT) {
        _Float16* Cc = (_Float16*)Cout;
#pragma unroll
        for (int j = 0; j < 4; ++j) Cc[r0 + (size_t)j * N] = (_Float16)acc[fm][fn][j];
      } else {
        float* Cc = (float*)Cout;
        const float bz = bias[col0 + ccol + fn * 16];
#pragma unroll
        for (int j = 0; j < 4; ++j) Cc[r0 + (size_t)j * N] = acc[fm][fn][j] + bz;
      }
    }
  }
}

// ---------------- LDS-tiled attention, k/v phase-split, one launch ----------------
// Block (after XCD remap): l -> branch (l/784), image ((l%784)/49), tile (l%49).
// 8x8 token tile; thread = (token, head): tok=tid>>2, head=tid&3.
// Halo H=8+2*dil rows^2, row = 16 granules x 16B (one branch's 128ch k OR v),
// stride 272B. Phase K: stage k, dots. Phase V: overwrite with v, softmax+PV.
__global__ __launch_bounds__(256) void attn_tile2(const _Float16* __restrict__ qkv,
                                                  _Float16* __restrict__ y) {
  __shared__ char kv[196 * 272];  // 53312 B (sized for dil=3)
  const int p = blockIdx.x;
  const int l = (p & 7) * 294 + (p >> 3);   // 2352 = 8*294, bijective
  const int branch = l / 784;
  const int rem = l - branch * 784;
  const int bimg = rem / 49;
  const int tile = rem - bimg * 49;
  const int dil = branch + 1;
  const int H = 8 + 2 * dil;
  const int NROW = H * H;
  const int cb = branch * 128;
  const int ty0 = (tile / 7) * 8, tx0 = (tile % 7) * 8;
  const int tid = threadIdx.x;
  const int head = tid & 3, tok = tid >> 2;
  const int ly = tok >> 3, lx = tok & 7;
  const size_t base = (size_t)bimg * 3136;
  const float scale = 0.17677669529663687f;  // 1/sqrt(32)

  // q load issued first (latency overlaps the k-staging loop)
  const int gty = ty0 + ly, gtx = tx0 + lx;
  const _Float16* qp = qkv + (base + gty * 56 + gtx) * ROWQKV + cb + head * 32;
  half2v qh[16];
  *(half8*)&qh[0] = *(const half8*)(qp);
  *(half8*)&qh[4] = *(const half8*)(qp + 8);
  *(half8*)&qh[8] = *(const half8*)(qp + 16);
  *(half8*)&qh[12] = *(const half8*)(qp + 24);

  const int NG = NROW * 16;  // 16B granules per phase

  // ---- phase K: stage k halo (zero-filled OOB -> logit 0 semantics) ----
  for (int g = tid; g < NG; g += 256) {
    const int r = g >> 4, sl = g & 15;
    const int gy = ty0 - dil + r / H;
    const int gx = tx0 - dil + r % H;
    uint4 val = make_uint4(0u, 0u, 0u, 0u);
    if ((unsigned)gy < 56u && (unsigned)gx < 56u)
      val = *(const uint4*)(qkv + (base + gy * 56 + gx) * ROWQKV + 384 + cb + sl * 8);
    *(uint4*)(kv + r * 272 + sl * 16) = val;
  }
  __syncthreads();

  int rtap[9];
#pragma unroll
  for (int j = 0; j < 9; ++j) {
    const int dy = j / 3 - 1, dx = j % 3 - 1;
    rtap[j] = (ly + dil + dy * dil) * H + (lx + dil + dx * dil);
  }

  float lg[9];
#pragma unroll
  for (int j = 0; j < 9; ++j) {
    const char* kp = kv + rtap[j] * 272 + head * 64;
    half2v kh[16];
    *(half8*)&kh[0] = *(const half8*)(kp);
    *(half8*)&kh[4] = *(const half8*)(kp + 16);
    *(half8*)&kh[8] = *(const half8*)(kp + 32);
    *(half8*)&kh[12] = *(const half8*)(kp + 48);
    float d = 0.f;
#if __has_builtin(__builtin_amdgcn_fdot2)
#pragma unroll
    for (int c = 0; c < 16; ++c) d = __builtin_amdgcn_fdot2(qh[c], kh[c], d, false);
#else
#pragma unroll
    for (int c = 0; c < 16; ++c)
      d += (float)qh[c][0] * (float)kh[c][0] + (float)qh[c][1] * (float)kh[c][1];
#endif
    lg[j] = d * scale;
  }
  __syncthreads();  // all k reads done before v overwrites the buffer

  // ---- phase V: stage v halo into the same buffer ----
  for (int g = tid; g < NG; g += 256) {
    const int r = g >> 4, sl = g & 15;
    const int gy = ty0 - dil + r / H;
    const int gx = tx0 - dil + r % H;
    uint4 val = make_uint4(0u, 0u, 0u, 0u);
    if ((unsigned)gy < 56u && (unsigned)gx < 56u)
      val = *(const uint4*)(qkv + (base + gy * 56 + gx) * ROWQKV + 768 + cb + sl * 8);
    *(uint4*)(kv + r * 272 + sl * 16) = val;
  }

  // softmax over the 9 logits while v-staging is in flight
  float m = lg[0];
#pragma unroll
  for (int j = 1; j < 9; ++j) m = fmaxf(m, lg[j]);
  float s = 0.f;
#pragma unroll
  for (int j = 0; j < 9; ++j) { lg[j] = expf(lg[j] - m); s += lg[j]; }
  const float rs = 1.f / s;

  __syncthreads();

  float out[32];
#pragma unroll
  for (int c = 0; c < 32; ++c) out[c] = 0.f;
#pragma unroll
  for (int j = 0; j < 9; ++j) {
    const char* vp = kv + rtap[j] * 272 + head * 64;
    half8 vh[4];
    vh[0] = *(const half8*)(vp);
    vh[1] = *(const half8*)(vp + 16);
    vh[2] = *(const half8*)(vp + 32);
    vh[3] = *(const half8*)(vp + 48);
    const float pw = lg[j];
#pragma unroll
    for (int g = 0; g < 4; ++g)
#pragma unroll
      for (int e = 0; e < 8; ++e) out[g * 8 + e] = fmaf(pw, (float)vh[g][e], out[g * 8 + e]);
  }

  _Float16* yp = y + (base + gty * 56 + gtx) * (size_t)CDIM + cb + head * 32;
  half8 oh[4];
#pragma unroll
  for (int g = 0; g < 4; ++g) {
#pragma unroll
    for (int e = 0; e < 8; ++e) oh[g][e] = (_Float16)(out[g * 8 + e] * rs);
    *(half8*)(yp + g * 8) = oh[g];
  }
}

extern "C" void kernel_launch(void* const* d_in, const int* in_sizes, int n_in,
                              void* d_out, int out_size, void* d_ws, size_t ws_size,
                              hipStream_t stream) {
  const float* x = (const float*)d_in[0];       // [16,56,56,384]
  const float* w_qkv = (const float*)d_in[1];   // [1152,384]
  const float* w_proj = (const float*)d_in[2];  // [384,384]
  const float* b_proj = (const float*)d_in[3];  // [384]
  float* out = (float*)d_out;                   // [50176,384]

  _Float16* xh = (_Float16*)d_ws;                     // 50176*384
  _Float16* wqh = xh + (size_t)NTOK * CDIM;           // 1152*384
  _Float16* wph = wqh + (size_t)ROWQKV * CDIM;        // 384*384
  _Float16* qkvh = wph + (size_t)CDIM * CDIM;         // 50176*1152
  _Float16* yh = qkvh + (size_t)NTOK * ROWQKV;        // 50176*384

  conv_all<<<2048, 256, 0, stream>>>(x, w_qkv, w_proj, xh, wqh, wph);

  gemm3<true><<<(NTOK / 128) * (ROWQKV / 128), 256, 0, stream>>>(
      xh, wqh, nullptr, qkvh, ROWQKV, CDIM);

  attn_tile2<<<2352, 256, 0, stream>>>(qkvh, yh);

  gemm3<false><<<(NTOK / 128) * (CDIM / 128), 256, 0, stream>>>(
      yh, wph, b_proj, out, CDIM, CDIM);
}